// Round 1
// 406.519 us; speedup vs baseline: 1.0065x; 1.0065x over previous
//
#include <hip/hip_runtime.h>
#include <math.h>

// out = M @ x with M = se3_exp(w, v, theta), x: [4, N] fp32 row-major, N = 16M.
// Memory-bound streaming: 256 MB read + 256 MB write -> ~80 us floor at ~6.5 TB/s
// (the harness's own 1-GB poison fills measure 6.39-6.59 TB/s on this box).
//
// R2 structure: SINGLE fused kernel.
//  - M (12 coefficients) is wave-uniform arithmetic on 7 scalars (w, v, theta).
//    Every thread computes it redundantly; the computation is issued AFTER the
//    8 nontemporal loads so it hides entirely under their latency. This removes
//    the second graph node (build kernel) and its dependency edge, plus the
//    d_ws round trip.
//  - 2x f32x4 per thread (8 16-B loads in flight/thread) for deeper MLP;
//    consecutive lanes still access consecutive 16 B within each instruction.
//  - Nontemporal loads/stores: touch-once streams, skip cache allocate.
//
// Note: __builtin_nontemporal_* requires a NATIVE clang vector type, not HIP's
// float4 class. Use ext_vector_type(4).

typedef float f32x4 __attribute__((ext_vector_type(4)));

__global__ __launch_bounds__(256) void se3_fused_kernel(
    const float* __restrict__ x,
    const float* __restrict__ w,
    const float* __restrict__ v,
    const float* __restrict__ th_p,
    float* __restrict__ out,
    int N)
{
    const int n4 = N >> 2;                       // number of f32x4 per row
    const int i0 = (int)blockIdx.x * ((int)blockDim.x * 2) + (int)threadIdx.x;
    const int i1 = i0 + (int)blockDim.x;

    const f32x4* x0p = (const f32x4*)(x);
    const f32x4* x1p = (const f32x4*)(x + (size_t)N);
    const f32x4* x2p = (const f32x4*)(x + 2 * (size_t)N);
    const f32x4* x3p = (const f32x4*)(x + 3 * (size_t)N);

    // Issue all global loads FIRST (addresses independent of M) so the
    // wave-uniform M computation below hides under their latency.
    f32x4 a0 = {}, b0 = {}, e0 = {}, d0 = {};
    f32x4 a1 = {}, b1 = {}, e1 = {}, d1 = {};
    const bool p0 = (i0 < n4);
    const bool p1 = (i1 < n4);
    if (p0) {
        a0 = __builtin_nontemporal_load(x0p + i0);
        b0 = __builtin_nontemporal_load(x1p + i0);
        e0 = __builtin_nontemporal_load(x2p + i0);
        d0 = __builtin_nontemporal_load(x3p + i0);
    }
    if (p1) {
        a1 = __builtin_nontemporal_load(x0p + i1);
        b1 = __builtin_nontemporal_load(x1p + i1);
        e1 = __builtin_nontemporal_load(x2p + i1);
        d1 = __builtin_nontemporal_load(x3p + i1);
    }

    // ---- M = se3_exp(w, v, theta), rows 0..2 (row 3 = [0,0,0,1]) ----
    // Uniform scalar loads -> s_load; VALU cost (~60 ops + sin/cos) is ~3 us
    // chip-wide, fully hidden under the streaming loads above.
    const float w0 = w[0], w1 = w[1], w2 = w[2];
    const float vv0 = v[0], vv1 = v[1], vv2 = v[2];
    const float th = th_p[0];
    const float s = sinf(th);
    const float c = cosf(th);
    const float omc = 1.0f - c;
    const float tms = th - s;

    const float kk00 = -(w1 * w1 + w2 * w2);
    const float kk11 = -(w0 * w0 + w2 * w2);
    const float kk22 = -(w0 * w0 + w1 * w1);
    const float kk01 = w0 * w1;
    const float kk02 = w0 * w2;
    const float kk12 = w1 * w2;

    // R = I + s*K + (1-c)*K^2
    const float r00 = 1.0f + omc * kk00;
    const float r01 = -s * w2 + omc * kk01;
    const float r02 =  s * w1 + omc * kk02;
    const float r10 =  s * w2 + omc * kk01;
    const float r11 = 1.0f + omc * kk11;
    const float r12 = -s * w0 + omc * kk12;
    const float r20 = -s * w1 + omc * kk02;
    const float r21 =  s * w0 + omc * kk12;
    const float r22 = 1.0f + omc * kk22;

    // V = th*I + (1-c)*K + (th-s)*K^2 ; t = V @ v
    const float V00 = th + tms * kk00;
    const float V01 = -omc * w2 + tms * kk01;
    const float V02 =  omc * w1 + tms * kk02;
    const float V10 =  omc * w2 + tms * kk01;
    const float V11 = th + tms * kk11;
    const float V12 = -omc * w0 + tms * kk12;
    const float V20 = -omc * w1 + tms * kk02;
    const float V21 =  omc * w0 + tms * kk12;
    const float V22 = th + tms * kk22;

    const float t0 = V00 * vv0 + V01 * vv1 + V02 * vv2;
    const float t1 = V10 * vv0 + V11 * vv1 + V12 * vv2;
    const float t2 = V20 * vv0 + V21 * vv1 + V22 * vv2;

    // ---- transform + store ----
    f32x4* o0p = (f32x4*)(out);
    f32x4* o1p = (f32x4*)(out + (size_t)N);
    f32x4* o2p = (f32x4*)(out + 2 * (size_t)N);
    f32x4* o3p = (f32x4*)(out + 3 * (size_t)N);

    if (p0) {
        const f32x4 y0 = r00 * a0 + r01 * b0 + r02 * e0 + t0 * d0;
        const f32x4 y1 = r10 * a0 + r11 * b0 + r12 * e0 + t1 * d0;
        const f32x4 y2 = r20 * a0 + r21 * b0 + r22 * e0 + t2 * d0;
        __builtin_nontemporal_store(y0, o0p + i0);
        __builtin_nontemporal_store(y1, o1p + i0);
        __builtin_nontemporal_store(y2, o2p + i0);
        __builtin_nontemporal_store(d0, o3p + i0);   // row 3 of M = [0,0,0,1]
    }
    if (p1) {
        const f32x4 y0 = r00 * a1 + r01 * b1 + r02 * e1 + t0 * d1;
        const f32x4 y1 = r10 * a1 + r11 * b1 + r12 * e1 + t1 * d1;
        const f32x4 y2 = r20 * a1 + r21 * b1 + r22 * e1 + t2 * d1;
        __builtin_nontemporal_store(y0, o0p + i1);
        __builtin_nontemporal_store(y1, o1p + i1);
        __builtin_nontemporal_store(y2, o2p + i1);
        __builtin_nontemporal_store(d1, o3p + i1);
    }

    // Tail for N % 4 != 0 (no-op at N = 16M).
    const int tail = N & 3;
    if (blockIdx.x == 0 && (int)threadIdx.x < tail) {
        const int j = (N & ~3) + (int)threadIdx.x;
        const float a = x[j];
        const float b = x[(size_t)N + j];
        const float e = x[2 * (size_t)N + j];
        const float d = x[3 * (size_t)N + j];
        out[j]                 = r00 * a + r01 * b + r02 * e + t0 * d;
        out[(size_t)N + j]     = r10 * a + r11 * b + r12 * e + t1 * d;
        out[2 * (size_t)N + j] = r20 * a + r21 * b + r22 * e + t2 * d;
        out[3 * (size_t)N + j] = d;
    }
}

extern "C" void kernel_launch(void* const* d_in, const int* in_sizes, int n_in,
                              void* d_out, int out_size, void* d_ws, size_t ws_size,
                              hipStream_t stream) {
    const float* x  = (const float*)d_in[0];   // [4, N]
    const float* w  = (const float*)d_in[1];   // [3]
    const float* v  = (const float*)d_in[2];   // [3]
    const float* th = (const float*)d_in[3];   // [1]
    float* out = (float*)d_out;                // [4, N]
    (void)d_ws; (void)ws_size;

    const int N = in_sizes[0] / 4;
    const int n4 = N / 4;
    const int per_block = 256 * 2;             // 2x f32x4 per thread
    int blocks = (n4 + per_block - 1) / per_block;
    if (blocks < 1) blocks = 1;

    se3_fused_kernel<<<blocks, 256, 0, stream>>>(x, w, v, th, out, N);
}